// Round 6
// baseline (55.854 us; speedup 1.0000x reference)
//
#include <hip/hip_runtime.h>

#define NUM_CLASSES 100000
#define FEAT_DIM    256
#define BATCH       16384
#define ALPHA       0.5f
#define EPS_        1e-6f

typedef float f4 __attribute__((ext_vector_type(4)));

// --- ws layout (bytes) ---
// Zeroed range: counts + head + nslots (contiguous, 800016 B)
#define OFF_COUNTS    0u                          // 100000 * 4 = 400000
#define OFF_HEAD      400000u                     // 100000 * 4 (sample_idx+1; 0 = empty)
#define OFF_NSLOTS    800000u                     // 4 (+12 pad)
#define OFF_ZERO_END  800016u                     // divisible by 16
// Not zeroed (written-before-read every call):
#define OFF_SLOT      OFF_ZERO_END                // 100000 * 4 slot_of
#define OFF_NEXT      (OFF_SLOT + 400000u)        // 16384 * 4 chain links
#define OFF_PART2     (OFF_NEXT + 65536u)         // 16384 * 4 per-slot loss partials

// K0: custom zero (hipMemsetAsync's fillBuffer costs ~60us fixed in-graph — never use it)
__global__ void zero_kernel(f4* __restrict__ p, int n) {
    int i = blockIdx.x * blockDim.x + threadIdx.x;
    if (i < n) p[i] = (f4){0.f, 0.f, 0.f, 0.f};
}

// K1: histogram + compact slot assignment + per-class linked chain of samples.
__global__ void count_slot_kernel(const int* __restrict__ target,
                                  int* __restrict__ counts,
                                  int* __restrict__ head,
                                  int* __restrict__ next,
                                  int* __restrict__ slot_of,
                                  int* __restrict__ nslots) {
    int i = blockIdx.x * blockDim.x + threadIdx.x;
    if (i < BATCH) {
        int t = target[i];
        int old = atomicAdd(&counts[t], 1);
        if (old == 0) slot_of[t] = atomicAdd(nslots, 1);
        int prev = atomicExch(&head[t], i + 1);   // push sample onto class chain
        next[i] = prev;
    }
}

// K2: wave per class row. Lane l owns cols {l, l+64, l+128, l+192} so every
// load/store instruction is 256B contiguous across the wave (coalesced dwords)
// — immune to the +1-float misalignment of out_centers. (The aligned(4) f4
// store compiled to stride-16 scalar stores: 25% store density, 1.7 TB/s.)
__global__ void rewrite_kernel(const float* __restrict__ centers,
                               const float* __restrict__ features,
                               const int*   __restrict__ counts,
                               const int*   __restrict__ head,
                               const int*   __restrict__ next,
                               const int*   __restrict__ slot_of,
                               float*       __restrict__ out_centers,  // d_out + 1
                               float*       __restrict__ partials2) {
    const int wave = threadIdx.x >> 6;
    const int lane = threadIdx.x & 63;
    const int row = blockIdx.x * 4 + wave;        // NUM_CLASSES % 4 == 0
    if (row >= NUM_CLASSES) return;

    const size_t base = (size_t)row * FEAT_DIM + lane;
    const float* crow = centers + base;
    float*       orow = out_centers + base;

    const float c0 = crow[0], c1 = crow[64], c2 = crow[128], c3 = crow[192];
    const int cnt = counts[row];                  // wave-uniform

    if (cnt == 0) {                               // ~85% of rows: streaming copy
        orow[0]   = c0;
        orow[64]  = c1;
        orow[128] = c2;
        orow[192] = c3;
        return;
    }

    float s0 = 0.f, s1 = 0.f, s2 = 0.f, s3 = 0.f, sq = 0.f;
    for (int j = head[row]; j != 0; j = next[j - 1]) {   // avg 1.1 iters, max ~8
        const float* frow = features + (size_t)(j - 1) * FEAT_DIM + lane;
        const float f0 = frow[0], f1 = frow[64], f2 = frow[128], f3 = frow[192];
        s0 += f0; s1 += f1; s2 += f2; s3 += f3;
        sq += f0*f0 + f1*f1 + f2*f2 + f3*f3;
    }

    const float fc  = (float)cnt;
    const float inv = ALPHA / (fc + EPS_);
    orow[0]   = c0 - inv * (fc * c0 - s0);
    orow[64]  = c1 - inv * (fc * c1 - s1);
    orow[128] = c2 - inv * (fc * c2 - s2);
    orow[192] = c3 - inv * (fc * c3 - s3);

    // complete loss partial: sum||f||^2 + cnt*||c||^2 - 2*c.sum_f
    float red = sq
              + fc * (c0*c0 + c1*c1 + c2*c2 + c3*c3)
              - 2.0f * (c0*s0 + c1*s1 + c2*s2 + c3*s3);
    #pragma unroll
    for (int off = 32; off > 0; off >>= 1)
        red += __shfl_down(red, off, 64);
    if (lane == 0) partials2[slot_of[row]] = red; // compact plain store
}

// K3: loss = sum of per-class partials / (B*D). ns <= 16384 -> 64KB read, 1 block.
__global__ void reduce_loss(const float* __restrict__ partials2,
                            const int*   __restrict__ nslots,
                            float* __restrict__ out) {
    const int ns = *nslots;
    float s = 0.0f;
    for (int i = threadIdx.x; i < ns; i += 1024) s += partials2[i];
    #pragma unroll
    for (int off = 32; off > 0; off >>= 1)
        s += __shfl_down(s, off, 64);
    __shared__ float wsum[16];
    const int lane = threadIdx.x & 63;
    const int wid  = threadIdx.x >> 6;
    if (lane == 0) wsum[wid] = s;
    __syncthreads();
    if (threadIdx.x == 0) {
        float tot = 0.0f;
        #pragma unroll
        for (int k = 0; k < 16; ++k) tot += wsum[k];
        out[0] = tot * (1.0f / ((float)BATCH * (float)FEAT_DIM));
    }
}

extern "C" void kernel_launch(void* const* d_in, const int* in_sizes, int n_in,
                              void* d_out, int out_size, void* d_ws, size_t ws_size,
                              hipStream_t stream) {
    const float* centers  = (const float*)d_in[0];
    const float* features = (const float*)d_in[1];
    const int*   target   = (const int*)d_in[2];

    float* out         = (float*)d_out;
    float* out_centers = out + 1;

    char* ws = (char*)d_ws;
    int*   counts    = (int*)(ws + OFF_COUNTS);
    int*   head      = (int*)(ws + OFF_HEAD);
    int*   nslots    = (int*)(ws + OFF_NSLOTS);
    int*   slot_of   = (int*)(ws + OFF_SLOT);
    int*   next      = (int*)(ws + OFF_NEXT);
    float* partials2 = (float*)(ws + OFF_PART2);

    const int nzero = (int)(OFF_ZERO_END / 16u);  // counts + head + nslots
    zero_kernel<<<(nzero + 255) / 256, 256, 0, stream>>>((f4*)ws, nzero);

    count_slot_kernel<<<(BATCH + 255) / 256, 256, 0, stream>>>(target, counts, head, next,
                                                               slot_of, nslots);

    rewrite_kernel<<<NUM_CLASSES / 4, 256, 0, stream>>>(centers, features, counts, head,
                                                        next, slot_of, out_centers, partials2);

    reduce_loss<<<1, 1024, 0, stream>>>(partials2, nslots, out);
}